// Round 1
// baseline (7363.135 us; speedup 1.0000x reference)
//
#include <hip/hip_runtime.h>
#include <stdint.h>

// Problem constants
#define BB   64
#define TT   250
#define INN  1024
#define HIDD 2048
#define OUTT 256

#define DECAYF 0.951229424500714f   // exp(-1/20)
#define ALPHAF 0.951229424500714f
#define LRF    1e-4f
#define WDF    0.01f
#define SCLF   0.2f

// d_out offsets (float elements), concatenated return order:
// l1_seq [64,250,2048], l2_seq [64,250,256], v1 [64,2048], v2 [64,256],
// l1_tr [64,2048], l2_tr [64,256]
#define O_L1SEQ 0
#define O_L2SEQ 32768000
#define O_V1    36864000
#define O_V2    36995072
#define O_L1TR  37011456
#define O_L2TR  37142528

// workspace layout (byte offsets), ~6.7 MB total
#define WS_PC1   0         // f32 [8][64][2048]  gemm1 split-K partials
#define WS_PC2   4194304   // f32 [16][64][256]  gemm2 split-K partials
#define WS_INTR  5242880   // f32 [64][1024]     in_tr state
#define WS_INTRT 5505024   // bf16 [1024][64]    in_tr transposed (B-operand for outer1)
#define WS_L1B   5636096   // bf16 [64][2048]    l1 spikes (A-operand for gemm2)
#define WS_L1TR  5898240   // bf16 [2][64][2048] l1_tr parity buffers
#define WS_L1TRT 6422528   // bf16 [2][2048][64] l1_tr transposed parity
#define WS_L2TRT 6946816   // bf16 [256][64]     l2_tr transposed

typedef __attribute__((ext_vector_type(8))) short short8v;
typedef __attribute__((ext_vector_type(4))) float float4v;

__device__ inline short f2bf(float f) {
  union { float f; uint32_t u; } c; c.f = f;
  uint32_t u = c.u + 0x7fffu + ((c.u >> 16) & 1u);  // RNE
  return (short)(u >> 16);
}

// ---- staging helpers (global -> LDS bf16, rows = output dim, padded stride) ----

// fp32 [64 rows x 128 cols] -> bf16 LDS [64][136]
__device__ inline void stage_f32_64x128(const float* __restrict__ src, int rowstride,
                                        short* dst, int tid) {
  for (int e = tid * 4; e < 8192; e += 1024) {
    int r = e >> 7, c = e & 127;
    float4 v = *(const float4*)(src + r * rowstride + c);
    short4 s;
    s.x = f2bf(v.x); s.y = f2bf(v.y); s.z = f2bf(v.z); s.w = f2bf(v.w);
    *(short4*)&dst[r * 136 + c] = s;
  }
}

// bf16 [64 rows x 128 cols] -> LDS [64][136]
__device__ inline void stage_bf_64x128(const short* __restrict__ src, int rowstride,
                                       short* dst, int tid) {
  for (int e = tid * 4; e < 8192; e += 1024) {
    int r = e >> 7, c = e & 127;
    *(short4*)&dst[r * 136 + c] = *(const short4*)(src + r * rowstride + c);
  }
}

// bf16 [128 rows x 64 cols] -> LDS [128][72]
__device__ inline void stage_bf_128x64(const short* __restrict__ src, short* dst, int tid) {
  for (int e = tid * 4; e < 8192; e += 1024) {
    int r = e >> 6, c = e & 63;
    *(short4*)&dst[r * 72 + c] = *(const short4*)(src + r * 64 + c);
  }
}

// ---- MFMA tile cores ----
// Operands stored [own-output-dim][k] in LDS. A rows = m, B rows = n.
// mfma_f32_16x16x32_bf16: A/B frag: lane holds row (lane&15), 8 contiguous k at
// k0=(lane>>4)*8; C/D: col=lane&15, row=(lane>>4)*4+reg.

// block computes [64 m x 64 n], K=128; wave wv covers n-tile wv. acc[4] = 4 m-tiles.
__device__ inline void mfma_64x64_k128(const short* As, const short* Bs, int tid,
                                       float4v acc[4]) {
  int lane = tid & 63, wv = tid >> 6;
  int mr = lane & 15, q = lane >> 4;
  float4v z = {0.f, 0.f, 0.f, 0.f};
  acc[0] = z; acc[1] = z; acc[2] = z; acc[3] = z;
#pragma unroll
  for (int kf = 0; kf < 4; kf++) {
    int koff = kf * 32 + q * 8;
    short8v bf = *(const short8v*)&Bs[(wv * 16 + mr) * 136 + koff];
#pragma unroll
    for (int mt = 0; mt < 4; mt++) {
      short8v af = *(const short8v*)&As[(mt * 16 + mr) * 136 + koff];
      acc[mt] = __builtin_amdgcn_mfma_f32_16x16x32_bf16(af, bf, acc[mt], 0, 0, 0);
    }
  }
}

// block computes [128 m x 128 n], K=64; wave wv covers n-tiles {2wv, 2wv+1}.
// acc[mt*2+n2] over 8 m-tiles.
__device__ inline void mfma_128x128_k64(const short* As, const short* Bs, int tid,
                                        float4v acc[16]) {
  int lane = tid & 63, wv = tid >> 6;
  int mr = lane & 15, q = lane >> 4;
  float4v z = {0.f, 0.f, 0.f, 0.f};
#pragma unroll
  for (int i = 0; i < 16; i++) acc[i] = z;
#pragma unroll
  for (int kf = 0; kf < 2; kf++) {
    int koff = kf * 32 + q * 8;
    short8v bf0 = *(const short8v*)&Bs[((wv * 2 + 0) * 16 + mr) * 72 + koff];
    short8v bf1 = *(const short8v*)&Bs[((wv * 2 + 1) * 16 + mr) * 72 + koff];
#pragma unroll
    for (int mt = 0; mt < 8; mt++) {
      short8v af = *(const short8v*)&As[(mt * 16 + mr) * 72 + koff];
      acc[mt * 2 + 0] = __builtin_amdgcn_mfma_f32_16x16x32_bf16(af, bf0, acc[mt * 2 + 0], 0, 0, 0);
      acc[mt * 2 + 1] = __builtin_amdgcn_mfma_f32_16x16x32_bf16(af, bf1, acc[mt * 2 + 1], 0, 0, 0);
    }
  }
}

// ---- init: zero state held in d_out (poisoned each launch) + in_tr in ws ----
__global__ __launch_bounds__(256) void k_init(float* __restrict__ out, char* __restrict__ ws) {
  int g = blockIdx.x * blockDim.x + threadIdx.x;
  int n = gridDim.x * blockDim.x;
  for (int e = g; e < BB * HIDD; e += n) { out[O_V1 + e] = 0.f; out[O_L1TR + e] = 0.f; }
  for (int e = g; e < BB * OUTT; e += n) { out[O_V2 + e] = 0.f; out[O_L2TR + e] = 0.f; }
  float* intr = (float*)(ws + WS_INTR);
  for (int e = g; e < BB * INN; e += n) intr[e] = 0.f;
}

// ---- kernel A: gemm1 split-K partials (256 blks) + in_tr update (16) + LIF2(t-1) (8) ----
__global__ __launch_bounds__(256) void kA(const float* __restrict__ x,
                                          const float* __restrict__ w_in,
                                          float* __restrict__ out,
                                          char* __restrict__ ws, int t) {
  __shared__ short lds[2 * 64 * 136];
  int bid = blockIdx.x, tid = threadIdx.x;
  if (bid < 256) {
    // cur1 partial: [64 b x 64 h] over K-chunk 128; A = x[b][k], B = w_in[h][k]
    int ht = bid >> 3, kc = bid & 7;
    int h0 = ht * 64, k0 = kc * 128;
    stage_f32_64x128(x + t * INN + k0, TT * INN, lds, tid);
    stage_f32_64x128(w_in + h0 * INN + k0, INN, lds + 64 * 136, tid);
    __syncthreads();
    float4v acc[4];
    mfma_64x64_k128(lds, lds + 64 * 136, tid, acc);
    float* pc1 = (float*)(ws + WS_PC1);
    int lane = tid & 63, wv = tid >> 6, mr = lane & 15, q = lane >> 4;
#pragma unroll
    for (int mt = 0; mt < 4; mt++)
#pragma unroll
      for (int r = 0; r < 4; r++) {
        int b = mt * 16 + q * 4 + r;
        pc1[(kc * 64 + b) * HIDD + h0 + wv * 16 + mr] = acc[mt][r];
      }
  } else if (bid < 272) {
    // in_tr(t) = d*in_tr + (1-d)*x_t ; also write transposed bf16 [i][b]
    float* intr = (float*)(ws + WS_INTR);
    short* intrT = (short*)(ws + WS_INTRT);
    int g = (bid - 256) * 256 + tid;
    for (int e = g; e < BB * INN; e += 4096) {
      int b = e >> 10, i = e & 1023;
      float xv = x[(b * TT + t) * INN + i];
      float nv = DECAYF * intr[e] + (1.0f - DECAYF) * xv;
      intr[e] = nv;
      intrT[i * 64 + b] = f2bf(nv);
    }
  } else {
    // LIF2 for step t-1 (deferred): reduce pcur2, update v2/l2_tr (in d_out), emit l2_seq
    if (t == 0) return;
    float* pc2 = (float*)(ws + WS_PC2);
    short* l2trT = (short*)(ws + WS_L2TRT);
    int g = (bid - 272) * 256 + tid;
    for (int e = g; e < BB * OUTT; e += 2048) {
      int b = e >> 8, o = e & 255;
      float s = 0.f;
#pragma unroll
      for (int kk = 0; kk < 16; kk++) s += pc2[(kk * 64 + b) * OUTT + o];
      float v = ALPHAF * out[O_V2 + e] + SCLF * s;
      float z = v > 1.0f ? 1.0f : 0.0f;
      v -= z;
      out[O_V2 + e] = v;
      out[O_L2SEQ + (b * TT + (t - 1)) * OUTT + o] = z;
      float tr = DECAYF * out[O_L2TR + e] + (1.0f - DECAYF) * z;
      out[O_L2TR + e] = tr;
      l2trT[o * 64 + b] = f2bf(tr);
    }
  }
}

// ---- kernel B: LIF1(t) (64 blks) + outer2/w_hid update for t-1 (32 blks) ----
__global__ __launch_bounds__(256) void kB(float* __restrict__ out, char* __restrict__ ws,
                                          float* __restrict__ w_hid, int t) {
  __shared__ short lds[2 * 128 * 72];
  int bid = blockIdx.x, tid = threadIdx.x;
  if (bid < 64) {
    float* pc1 = (float*)(ws + WS_PC1);
    short* l1b = (short*)(ws + WS_L1B);
    short* l1tr = (short*)(ws + WS_L1TR) + (t & 1) * BB * HIDD;
    short* l1trT = (short*)(ws + WS_L1TRT) + (t & 1) * BB * HIDD;
    int g = bid * 256 + tid;          // 16384 threads, 8 h each
    int b = g >> 8, h0 = (g & 255) * 8;
    float av[8] = {0.f, 0.f, 0.f, 0.f, 0.f, 0.f, 0.f, 0.f};
#pragma unroll
    for (int kk = 0; kk < 8; kk++) {
      const float* p = &pc1[(kk * 64 + b) * HIDD + h0];
      float4 u = *(const float4*)p;
      float4 w = *(const float4*)(p + 4);
      av[0] += u.x; av[1] += u.y; av[2] += u.z; av[3] += u.w;
      av[4] += w.x; av[5] += w.y; av[6] += w.z; av[7] += w.w;
    }
#pragma unroll
    for (int j = 0; j < 8; j++) {
      int h = h0 + j;
      int e = b * HIDD + h;
      float v = ALPHAF * out[O_V1 + e] + SCLF * av[j];
      float z = v > 1.0f ? 1.0f : 0.0f;
      v -= z;
      out[O_V1 + e] = v;
      out[O_L1SEQ + (b * TT + t) * HIDD + h] = z;
      l1b[e] = f2bf(z);
      float tr = DECAYF * out[O_L1TR + e] + (1.0f - DECAYF) * z;
      out[O_L1TR + e] = tr;
      short sb = f2bf(tr);
      l1tr[e] = sb;
      l1trT[h * 64 + b] = sb;
    }
  } else {
    // w_hid += LR*(l2_tr(t-1)^T @ l1_tr(t-1) / B - WD*w_hid)
    if (t == 0) return;
    int idx = bid - 64;               // 0..31 -> tiles [128 o][128 h]
    int ob = idx >> 4, hb = idx & 15;
    int o0 = ob * 128, h0 = hb * 128;
    short* l2trT = (short*)(ws + WS_L2TRT);
    short* l1trTp = (short*)(ws + WS_L1TRT) + ((t - 1) & 1) * BB * HIDD;
    stage_bf_128x64(l2trT + o0 * 64, lds, tid);
    stage_bf_128x64(l1trTp + h0 * 64, lds + 128 * 72, tid);
    __syncthreads();
    float4v acc[16];
    mfma_128x128_k64(lds, lds + 128 * 72, tid, acc);
    int lane = tid & 63, wv = tid >> 6, mr = lane & 15, q = lane >> 4;
#pragma unroll
    for (int mt = 0; mt < 8; mt++)
#pragma unroll
      for (int n2 = 0; n2 < 2; n2++)
#pragma unroll
        for (int r = 0; r < 4; r++) {
          int o = o0 + mt * 16 + q * 4 + r;
          int h = h0 + (wv * 2 + n2) * 16 + mr;
          int e = o * HIDD + h;
          float w = w_hid[e];
          w_hid[e] = w * (1.0f - LRF * WDF) + (LRF / 64.0f) * acc[mt * 2 + n2][r];
        }
  }
}

// ---- kernel C: gemm2 split-K partials (64 blks) + outer1/w_in update for t (128 blks) ----
__global__ __launch_bounds__(256) void kC(float* __restrict__ w_in,
                                          const float* __restrict__ w_hid,
                                          char* __restrict__ ws, int t) {
  __shared__ short lds[2 * 128 * 72];
  int bid = blockIdx.x, tid = threadIdx.x;
  if (bid < 64) {
    // cur2 partial: [64 b x 64 o] over K-chunk 128; A = l1[b][h], B = w_hid[o][h]
    int ot = bid >> 4, kc = bid & 15;
    int o0 = ot * 64, k0 = kc * 128;
    short* l1b = (short*)(ws + WS_L1B);
    stage_bf_64x128(l1b + k0, HIDD, lds, tid);
    stage_f32_64x128(w_hid + o0 * HIDD + k0, HIDD, lds + 64 * 136, tid);
    __syncthreads();
    float4v acc[4];
    mfma_64x64_k128(lds, lds + 64 * 136, tid, acc);
    float* pc2 = (float*)(ws + WS_PC2);
    int lane = tid & 63, wv = tid >> 6, mr = lane & 15, q = lane >> 4;
#pragma unroll
    for (int mt = 0; mt < 4; mt++)
#pragma unroll
      for (int r = 0; r < 4; r++) {
        int b = mt * 16 + q * 4 + r;
        pc2[(kc * 64 + b) * OUTT + o0 + wv * 16 + mr] = acc[mt][r];
      }
  } else {
    // w_in += LR*(l1_tr(t)^T @ in_tr(t) / B - WD*w_in)
    int idx = bid - 64;               // 0..127 -> tiles [128 h][128 i]
    int hb = idx >> 3, ib = idx & 7;
    int h0 = hb * 128, i0 = ib * 128;
    short* l1trT = (short*)(ws + WS_L1TRT) + (t & 1) * BB * HIDD;
    short* intrT = (short*)(ws + WS_INTRT);
    stage_bf_128x64(l1trT + h0 * 64, lds, tid);
    stage_bf_128x64(intrT + i0 * 64, lds + 128 * 72, tid);
    __syncthreads();
    float4v acc[16];
    mfma_128x128_k64(lds, lds + 128 * 72, tid, acc);
    int lane = tid & 63, wv = tid >> 6, mr = lane & 15, q = lane >> 4;
#pragma unroll
    for (int mt = 0; mt < 8; mt++)
#pragma unroll
      for (int n2 = 0; n2 < 2; n2++)
#pragma unroll
        for (int r = 0; r < 4; r++) {
          int h = h0 + mt * 16 + q * 4 + r;
          int i = i0 + (wv * 2 + n2) * 16 + mr;
          int e = h * INN + i;
          float w = w_in[e];
          w_in[e] = w * (1.0f - LRF * WDF) + (LRF / 64.0f) * acc[mt * 2 + n2][r];
        }
  }
}

// ---- epilogue: LIF2 for the final step (t-1 = 249) ----
__global__ __launch_bounds__(256) void kE(float* __restrict__ out, char* __restrict__ ws) {
  float* pc2 = (float*)(ws + WS_PC2);
  int g = blockIdx.x * 256 + threadIdx.x;
  const int t = TT;
  for (int e = g; e < BB * OUTT; e += 2048) {
    int b = e >> 8, o = e & 255;
    float s = 0.f;
#pragma unroll
    for (int kk = 0; kk < 16; kk++) s += pc2[(kk * 64 + b) * OUTT + o];
    float v = ALPHAF * out[O_V2 + e] + SCLF * s;
    float z = v > 1.0f ? 1.0f : 0.0f;
    v -= z;
    out[O_V2 + e] = v;
    out[O_L2SEQ + (b * TT + (t - 1)) * OUTT + o] = z;
    float tr = DECAYF * out[O_L2TR + e] + (1.0f - DECAYF) * z;
    out[O_L2TR + e] = tr;
  }
}

extern "C" void kernel_launch(void* const* d_in, const int* in_sizes, int n_in,
                              void* d_out, int out_size, void* d_ws, size_t ws_size,
                              hipStream_t stream) {
  const float* x = (const float*)d_in[0];
  float* w_in = (float*)d_in[1];    // mutated in place; harness restores each launch
  float* w_hid = (float*)d_in[2];
  float* out = (float*)d_out;
  char* ws = (char*)d_ws;

  hipLaunchKernelGGL(k_init, dim3(256), dim3(256), 0, stream, out, ws);
  for (int t = 0; t < TT; t++) {
    hipLaunchKernelGGL(kA, dim3(280), dim3(256), 0, stream, x, w_in, out, ws, t);
    hipLaunchKernelGGL(kB, dim3(96), dim3(256), 0, stream, out, ws, w_hid, t);
    hipLaunchKernelGGL(kC, dim3(192), dim3(256), 0, stream, w_in, w_hid, ws, t);
  }
  hipLaunchKernelGGL(kE, dim3(8), dim3(256), 0, stream, out, ws);
}